// Round 1
// baseline (272.898 us; speedup 1.0000x reference)
//
#include <hip/hip_runtime.h>

#define KCODES 512
#define DIM    64
#define NVEC   65536   // 64 * 32 * 32
#define BLOCK  256
#define TAU    0.0625f

// ---------------------------------------------------------------------------
// Kernel 1: e2[k] = ||codebook[k]||^2  (fp32; error ~1e-5 folded into TAU)
// ---------------------------------------------------------------------------
__global__ void e2_kernel(const float* __restrict__ cb, float* __restrict__ e2) {
    int k = blockIdx.x * 64 + threadIdx.x;
    if (k >= KCODES) return;
    const float4* row = (const float4*)(cb + (size_t)k * DIM);
    float s = 0.f;
#pragma unroll
    for (int i = 0; i < DIM / 4; ++i) {
        float4 v = row[i];
        s += v.x * v.x + v.y * v.y + v.z * v.z + v.w * v.w;
    }
    e2[k] = s;
}

// ---------------------------------------------------------------------------
// Kernel 2: per-thread nearest-code search + gather/scatter of winning row.
// One thread = one (b, n) vector. Codebook staged in LDS, 256 rows/phase.
// ---------------------------------------------------------------------------
__launch_bounds__(BLOCK, 1)
__global__ void vq_kernel(const float* __restrict__ x,
                          const float* __restrict__ cb,
                          const float* __restrict__ e2g,
                          float* __restrict__ out) {
    __shared__ float lds_cb[256 * DIM];   // 64 KB: half the codebook per phase

    const int v = blockIdx.x * BLOCK + threadIdx.x;
    const int b = v >> 10;          // 1024 spatial positions per batch
    const int n = v & 1023;
    const float* xp = x + (size_t)b * 65536 + n;

    // Load this vector's 64 components (stride 1024 per d; coalesced over lanes)
    float xv[DIM];
#pragma unroll
    for (int d = 0; d < DIM; ++d) xv[d] = xp[(size_t)d * 1024];

    float best1 = 3.4e38f, best2 = 3.4e38f;
    int   bi1 = 0, bi2 = 0;

    for (int ph = 0; ph < 2; ++ph) {
        __syncthreads();
        // Cooperative coalesced load of 256 rows (64 KB) into LDS
        const float4* src = (const float4*)(cb + (size_t)ph * 256 * DIM);
        float4*       dst = (float4*)lds_cb;
#pragma unroll
        for (int j = 0; j < 16; ++j)
            dst[threadIdx.x + j * BLOCK] = src[threadIdx.x + j * BLOCK];
        __syncthreads();

        for (int kk = 0; kk < 256; ++kk) {
            const int k = ph * 256 + kk;
            const float* er = lds_cb + kk * DIM;   // uniform addr -> LDS broadcast
            float a0 = 0.f, a1 = 0.f, a2 = 0.f, a3 = 0.f;
#pragma unroll
            for (int i = 0; i < DIM; i += 4) {
                a0 += xv[i + 0] * er[i + 0];
                a1 += xv[i + 1] * er[i + 1];
                a2 += xv[i + 2] * er[i + 2];
                a3 += xv[i + 3] * er[i + 3];
            }
            // argmin(||x-e||^2) == argmin(e2 - 2 x.e)  (x2 term is constant)
            float d = e2g[k] - 2.f * ((a0 + a1) + (a2 + a3));
            if (d < best1) { best2 = best1; bi2 = bi1; best1 = d; bi1 = k; }
            else if (d < best2) { best2 = d; bi2 = k; }
        }
    }

    // Near-tie: re-resolve the top-2 candidates with exact fp64 accumulation.
    // fp32 pass error is < ~1e-3 worst-case, far below TAU, so the true argmin
    // is guaranteed to be one of {bi1, bi2} (3-way ties inside TAU are ~1e-4
    // probability over the whole problem).
    if (best2 - best1 < TAU) {
        const float* r1 = cb + (size_t)bi1 * DIM;
        const float* r2 = cb + (size_t)bi2 * DIM;
        double q1 = 0.0, s1 = 0.0, q2 = 0.0, s2 = 0.0;
#pragma unroll 8
        for (int i = 0; i < DIM; ++i) {
            double xd = (double)xv[i];
            double e1 = (double)r1[i];
            double e2v = (double)r2[i];
            q1 += e1 * e1;  s1 += xd * e1;
            q2 += e2v * e2v; s2 += xd * e2v;
        }
        double D1 = q1 - 2.0 * s1;
        double D2 = q2 - 2.0 * s2;
        if (D2 < D1 || (D2 == D1 && bi2 < bi1)) bi1 = bi2;  // numpy: first index wins
    }

    // Write codebook[bi1] to out[b, :, n] — row gather (L2-hot) + coalesced stores
    const float4* crow = (const float4*)(cb + (size_t)bi1 * DIM);
    float* op = out + (size_t)b * 65536 + n;
#pragma unroll
    for (int q = 0; q < DIM / 4; ++q) {
        float4 val = crow[q];
        op[(size_t)(q * 4 + 0) * 1024] = val.x;
        op[(size_t)(q * 4 + 1) * 1024] = val.y;
        op[(size_t)(q * 4 + 2) * 1024] = val.z;
        op[(size_t)(q * 4 + 3) * 1024] = val.w;
    }
}

extern "C" void kernel_launch(void* const* d_in, const int* in_sizes, int n_in,
                              void* d_out, int out_size, void* d_ws, size_t ws_size,
                              hipStream_t stream) {
    const float* x  = (const float*)d_in[0];   // (64, 64, 32, 32) fp32
    const float* cb = (const float*)d_in[1];   // (512, 64) fp32
    float* e2  = (float*)d_ws;                 // 512 floats scratch
    float* out = (float*)d_out;                // (64, 64, 32, 32) fp32

    e2_kernel<<<(KCODES + 63) / 64, 64, 0, stream>>>(cb, e2);
    vq_kernel<<<NVEC / BLOCK, BLOCK, 0, stream>>>(x, cb, e2, out);
}

// Round 2
// 109.998 us; speedup vs baseline: 2.4810x; 2.4810x over previous
//
#include <hip/hip_runtime.h>

#define KCODES 512
#define DIM    64
#define NVEC   65536          // 64 * 32 * 32
#define TAU    0.1f

typedef __attribute__((ext_vector_type(8))) short   short8;  // 8 bf16 = 4 VGPRs
typedef __attribute__((ext_vector_type(4))) float   f32x4;

__device__ __forceinline__ unsigned short f2bf(float f) {    // fp32 -> bf16 RNE
    unsigned int u = __builtin_bit_cast(unsigned int, f);
    u += 0x7fffu + ((u >> 16) & 1u);
    return (unsigned short)(u >> 16);
}
__device__ __forceinline__ float bf2f(unsigned short h) {
    unsigned int u = ((unsigned int)h) << 16;
    return __builtin_bit_cast(float, u);
}

// ---------------------------------------------------------------------------
// Prep 1: split codebook into bf16 hi/lo (x ~= hi + lo, lo = rne(x - f32(hi)))
// ---------------------------------------------------------------------------
__global__ void prep_convert(const float* __restrict__ cb,
                             unsigned short* __restrict__ cbh,
                             unsigned short* __restrict__ cbl) {
    int e = blockIdx.x * 256 + threadIdx.x;   // 32768 elements
    float v = cb[e];
    unsigned short h = f2bf(v);
    cbh[e] = h;
    cbl[e] = f2bf(v - bf2f(h));
}

// ---------------------------------------------------------------------------
// Prep 2: e2[k] = ||e_k||^2 in fp64, stored fp32. One 64-lane block per code.
// ---------------------------------------------------------------------------
__global__ void prep_e2(const float* __restrict__ cb, float* __restrict__ e2) {
    int k = blockIdx.x;
    float v = cb[k * DIM + threadIdx.x];
    double p = (double)v * (double)v;
#pragma unroll
    for (int off = 32; off > 0; off >>= 1) p += __shfl_down(p, off, 64);
    if (threadIdx.x == 0) e2[k] = (float)p;
}

// ---------------------------------------------------------------------------
// Main: block = 64 vectors. 4 waves: wave w -> vector-half (w>>1), code-half
// (w&1). Each wave: 32 vectors (2 n-tiles) x 256 codes (16 code-tiles).
// B (x) fragments live in registers; A (codebook bf16) streamed from L2.
// dist = e2[k] - 2*x.e  via 3-term bf16 MFMA; top-2 + fp64 tie re-resolve.
// ---------------------------------------------------------------------------
__launch_bounds__(256, 4)
__global__ void vq_main(const float* __restrict__ x,
                        const float* __restrict__ cb,
                        const unsigned short* __restrict__ cbh,
                        const unsigned short* __restrict__ cbl,
                        const float* __restrict__ e2g,
                        float* __restrict__ out) {
    __shared__ float s_f1[2][64], s_f2[2][64];
    __shared__ int   s_i1[2][64], s_i2[2][64];
    __shared__ int   s_win[64];

    const int tid   = threadIdx.x;
    const int wave  = tid >> 6;
    const int lane  = tid & 63;
    const int half  = wave >> 1;     // vector half (0: n 0..31, 1: n 32..63)
    const int chalf = wave & 1;      // code half (0: k 0..255, 1: k 256..511)
    const int quad  = lane >> 4;
    const int l16   = lane & 15;

    const int v0    = blockIdx.x * 64;
    const int b     = v0 >> 10;
    const int nbase = v0 & 1023;
    const float* xb = x + (size_t)b * 65536;

    // ---- B fragments: B[k=quad*8+j (+32*koff)][n=l16], per n-tile, hi/lo ----
    short8 Bh[2][2], Bl[2][2];
#pragma unroll
    for (int nt = 0; nt < 2; ++nt) {
        const int n_g = nbase + half * 32 + nt * 16 + l16;
#pragma unroll
        for (int ko = 0; ko < 2; ++ko) {
#pragma unroll
            for (int j = 0; j < 8; ++j) {
                const int d = quad * 8 + j + ko * 32;
                float f = xb[(size_t)d * 1024 + n_g];
                unsigned short h = f2bf(f);
                Bh[nt][ko][j] = (short)h;
                Bl[nt][ko][j] = (short)f2bf(f - bf2f(h));
            }
        }
    }

    // ---- running top-2 per n-tile ----
    float f1[2] = {3.4e38f, 3.4e38f}, f2_[2] = {3.4e38f, 3.4e38f};
    int   i1[2] = {0, 0},             i2_[2] = {0, 0};

    for (int tile = 0; tile < 16; ++tile) {
        const int codebase = chalf * 256 + tile * 16;
        const unsigned short* arow = cbh + ((size_t)(codebase + l16)) * DIM + quad * 8;
        const unsigned short* lrow = cbl + ((size_t)(codebase + l16)) * DIM + quad * 8;
        short8 Ah0 = *(const short8*)(arow);
        short8 Ah1 = *(const short8*)(arow + 32);
        short8 Al0 = *(const short8*)(lrow);
        short8 Al1 = *(const short8*)(lrow + 32);
        f32x4 e2v  = *(const f32x4*)(e2g + codebase + quad * 4);

#pragma unroll
        for (int nt = 0; nt < 2; ++nt) {
            f32x4 aa = {0.f, 0.f, 0.f, 0.f};
            f32x4 ab = {0.f, 0.f, 0.f, 0.f};
            aa = __builtin_amdgcn_mfma_f32_16x16x32_bf16(Ah0, Bh[nt][0], aa, 0, 0, 0);
            ab = __builtin_amdgcn_mfma_f32_16x16x32_bf16(Ah1, Bh[nt][1], ab, 0, 0, 0);
            aa = __builtin_amdgcn_mfma_f32_16x16x32_bf16(Ah0, Bl[nt][0], aa, 0, 0, 0);
            ab = __builtin_amdgcn_mfma_f32_16x16x32_bf16(Ah1, Bl[nt][1], ab, 0, 0, 0);
            aa = __builtin_amdgcn_mfma_f32_16x16x32_bf16(Al0, Bh[nt][0], aa, 0, 0, 0);
            ab = __builtin_amdgcn_mfma_f32_16x16x32_bf16(Al1, Bh[nt][1], ab, 0, 0, 0);
#pragma unroll
            for (int r = 0; r < 4; ++r) {
                float dd = e2v[r] - 2.f * (aa[r] + ab[r]);
                int   id = codebase + quad * 4 + r;
                if (dd < f1[nt]) { f2_[nt] = f1[nt]; i2_[nt] = i1[nt]; f1[nt] = dd; i1[nt] = id; }
                else if (dd < f2_[nt]) { f2_[nt] = dd; i2_[nt] = id; }
            }
        }
    }

    // ---- cross-quad butterfly merge (lanes {c,c+16,c+32,c+48} same vector) --
#pragma unroll
    for (int nt = 0; nt < 2; ++nt) {
#pragma unroll
        for (int delta = 16; delta <= 32; delta <<= 1) {
            float of1 = __shfl_xor(f1[nt], delta, 64);
            int   oi1 = __shfl_xor(i1[nt], delta, 64);
            float of2 = __shfl_xor(f2_[nt], delta, 64);
            int   oi2 = __shfl_xor(i2_[nt], delta, 64);
            bool o1_first = (of1 < f1[nt]) || (of1 == f1[nt] && oi1 < i1[nt]);
            if (o1_first) {
                bool keep = (f1[nt] < of2) || (f1[nt] == of2 && i1[nt] < oi2);
                f2_[nt] = keep ? f1[nt] : of2;
                i2_[nt] = keep ? i1[nt] : oi2;
                f1[nt] = of1; i1[nt] = oi1;
            } else {
                bool o1_second = (of1 < f2_[nt]) || (of1 == f2_[nt] && oi1 < i2_[nt]);
                if (o1_second) { f2_[nt] = of1; i2_[nt] = oi1; }
            }
        }
        if (quad == 0) {   // lanes 0..15 publish per (vector, code-half)
            int vloc = half * 32 + nt * 16 + l16;
            s_f1[chalf][vloc] = f1[nt]; s_i1[chalf][vloc] = i1[nt];
            s_f2[chalf][vloc] = f2_[nt]; s_i2[chalf][vloc] = i2_[nt];
        }
    }
    __syncthreads();

    // ---- final merge across code-halves + fp64 tie re-resolve -------------
    if (tid < 64) {
        const int v = tid;
        float F1 = s_f1[0][v], F2 = s_f2[0][v];
        int   I1 = s_i1[0][v], I2 = s_i2[0][v];
        float of1 = s_f1[1][v], of2 = s_f2[1][v];
        int   oi1 = s_i1[1][v], oi2 = s_i2[1][v];
        bool o1_first = (of1 < F1) || (of1 == F1 && oi1 < I1);
        if (o1_first) {
            bool keep = (F1 < of2) || (F1 == of2 && I1 < oi2);
            F2 = keep ? F1 : of2;  I2 = keep ? I1 : oi2;
            F1 = of1; I1 = oi1;
        } else if ((of1 < F2) || (of1 == F2 && oi1 < I2)) {
            F2 = of1; I2 = oi1;
        }
        int win = I1;
        if (F2 - F1 < TAU) {   // exact fp64 re-resolution of the two candidates
            const float* xr = xb + nbase + v;
            const float* r1 = cb + (size_t)I1 * DIM;
            const float* r2 = cb + (size_t)I2 * DIM;
            double q1 = 0.0, s1 = 0.0, q2 = 0.0, s2 = 0.0;
            for (int d = 0; d < DIM; ++d) {
                double xd = (double)xr[(size_t)d * 1024];
                double e1 = (double)r1[d], e2v2 = (double)r2[d];
                q1 += e1 * e1;   s1 += xd * e1;
                q2 += e2v2 * e2v2; s2 += xd * e2v2;
            }
            double D1 = q1 - 2.0 * s1, D2 = q2 - 2.0 * s2;
            if (D2 < D1 || (D2 == D1 && I2 < I1)) win = I2;
        }
        s_win[v] = win;
    }
    __syncthreads();

    // ---- output: out[b, d, nbase+n] = cb[win[n]][d], coalesced over n ------
    {
        const int n  = tid & 63;
        const int dq = tid >> 6;
        const float4* crow = (const float4*)(cb + (size_t)s_win[n] * DIM);
        float* op = out + (size_t)b * 65536 + nbase + n;
#pragma unroll
        for (int i = 0; i < 4; ++i) {
            const int d0 = dq * 16 + i * 4;
            float4 val = crow[d0 >> 2];
            op[(size_t)(d0 + 0) * 1024] = val.x;
            op[(size_t)(d0 + 1) * 1024] = val.y;
            op[(size_t)(d0 + 2) * 1024] = val.z;
            op[(size_t)(d0 + 3) * 1024] = val.w;
        }
    }
}

extern "C" void kernel_launch(void* const* d_in, const int* in_sizes, int n_in,
                              void* d_out, int out_size, void* d_ws, size_t ws_size,
                              hipStream_t stream) {
    const float* x  = (const float*)d_in[0];   // (64, 64, 32, 32) fp32
    const float* cb = (const float*)d_in[1];   // (512, 64) fp32
    float* out = (float*)d_out;

    // workspace: cb_hi (64KB) | cb_lo (64KB) | e2 (2KB)  = 133120 B
    unsigned short* cbh = (unsigned short*)d_ws;
    unsigned short* cbl = cbh + KCODES * DIM;
    float*          e2  = (float*)(cbl + KCODES * DIM);

    prep_convert<<<(KCODES * DIM) / 256, 256, 0, stream>>>(cb, cbh, cbl);
    prep_e2<<<KCODES, 64, 0, stream>>>(cb, e2);
    vq_main<<<NVEC / 64, 256, 0, stream>>>(x, cb, cbh, cbl, e2, out);
}